// Round 2
// baseline (181.348 us; speedup 1.0000x reference)
//
#include <hip/hip_runtime.h>
#include <math.h>

#define BSZ 2
#define NH 16
#define SEQ 4096
#define DH 64
#define BLK 64
#define NB (SEQ / BLK)      // 64
#define NG 256              // global keys
#define NKEY (BLK + NG)     // 320
#define NEGV -10000.0f
#define KSTR 72             // LDS row stride (fp16 elems) for K rows: 144B, 16B aligned
#define PSTR2 168           // LDS row stride for P / VT chunk: 336B, 16B aligned

typedef _Float16 f16x8 __attribute__((ext_vector_type(8)));
typedef _Float16 f16x4 __attribute__((ext_vector_type(4)));
typedef float floatx4 __attribute__((ext_vector_type(4)));

// global-key g (0..255) -> source sequence row within this (b,h)
__device__ __forceinline__ int gather_row(int g) {
    int j = g >> 2;
    int p = g & 3;
    return j * BLK + (p ? (BLK - 4 + p) : 0);   // {0, 61, 62, 63} + 64*j
}

__global__ __launch_bounds__(256, 2)
void sparse_attn_kernel(const float* __restrict__ Q, const float* __restrict__ K,
                        const float* __restrict__ V, const float* __restrict__ M,
                        float* __restrict__ O)
{
    const int wg   = blockIdx.x;          // 0..2047
    const int nblk = wg & (NB - 1);       // query block within head
    const int bh   = wg >> 6;             // 0..31
    const int b    = bh >> 4;             // /NH

    const size_t hoff = (size_t)bh * SEQ * DH;
    const float* Qh = Q + hoff;
    const float* Kh = K + hoff;
    const float* Vh = V + hoff;
    float*       Oh = O + hoff;
    const float* Mb = M + (size_t)b * SEQ;

    // LDS: K rows (320 x 72 f16 = 46080B). After QK, region reused for
    // P (64 x 168) + VT chunk (64 x 168) = 43008B. MaskAdd separate.
    __shared__ _Float16 Ksh[NKEY * KSTR];
    __shared__ float    MaskAdd[NKEY];
    _Float16* Psh = Ksh;                   // 64*168 elems
    _Float16* VTc = Ksh + 64 * PSTR2;      // 64*168 elems, 16B-aligned base

    const int tid  = threadIdx.x;
    const int lane = tid & 63;
    const int wv   = tid >> 6;             // wave 0..3 -> query rows wv*16..+15
    const int m    = lane & 15;
    const int quad = lane >> 4;

    // ---- stage K (local block rows 0..63, global gather rows 64..319) as fp16 ----
    for (int i = tid; i < NKEY * 16; i += 256) {
        int row = i >> 4;
        int c4  = (i & 15) << 2;
        int srow = (row < BLK) ? (nblk * BLK + row) : gather_row(row - BLK);
        const float4 f = *(const float4*)(Kh + (size_t)srow * DH + c4);
        f16x4 o4;
        o4[0] = (_Float16)f.x; o4[1] = (_Float16)f.y;
        o4[2] = (_Float16)f.z; o4[3] = (_Float16)f.w;
        *(f16x4*)(&Ksh[row * KSTR + c4]) = o4;
    }
    // ---- mask additive terms for all 320 keys ----
    for (int i = tid; i < NKEY; i += 256) {
        int srow = (i < BLK) ? (nblk * BLK + i) : gather_row(i - BLK);
        MaskAdd[i] = (Mb[srow] == 0.0f) ? NEGV : 0.0f;
    }

    // ---- Q fragments direct from global, hi/lo fp16 split (accuracy) ----
    const int qrow = nblk * BLK + wv * 16 + m;
    f16x8 qhf[2], qlf[2];
    #pragma unroll
    for (int c = 0; c < 2; ++c) {
        const float* src = Qh + (size_t)qrow * DH + c * 32 + quad * 8;
        float4 f0 = *(const float4*)(src);
        float4 f1 = *(const float4*)(src + 4);
        float vals[8] = {f0.x, f0.y, f0.z, f0.w, f1.x, f1.y, f1.z, f1.w};
        #pragma unroll
        for (int j = 0; j < 8; ++j) {
            _Float16 hi = (_Float16)vals[j];
            float    lo = vals[j] - (float)hi;
            qhf[c][j] = hi;
            qlf[c][j] = (_Float16)lo;
        }
    }

    __syncthreads();

    // ---- QK^T: 20 key tiles x 2 k-chunks, Q split into hi+lo ----
    floatx4 acc[20] = {};
    #pragma unroll
    for (int t = 0; t < 20; ++t) {
        #pragma unroll
        for (int c = 0; c < 2; ++c) {
            f16x8 kf = *(const f16x8*)(&Ksh[(t * 16 + m) * KSTR + c * 32 + quad * 8]);
            acc[t] = __builtin_amdgcn_mfma_f32_16x16x32_f16(qhf[c], kf, acc[t], 0, 0, 0);
            acc[t] = __builtin_amdgcn_mfma_f32_16x16x32_f16(qlf[c], kf, acc[t], 0, 0, 0);
        }
    }

    // ---- softmax over 320 keys; lane holds rows (wv*16+quad*4+r), cols (t*16+m) ----
    float rmax[4] = {-3e38f, -3e38f, -3e38f, -3e38f};
    #pragma unroll
    for (int t = 0; t < 20; ++t) {
        float ma = MaskAdd[t * 16 + m];
        #pragma unroll
        for (int r = 0; r < 4; ++r) {
            acc[t][r] += ma;
            rmax[r] = fmaxf(rmax[r], acc[t][r]);
        }
    }
    #pragma unroll
    for (int off = 8; off >= 1; off >>= 1) {
        #pragma unroll
        for (int r = 0; r < 4; ++r)
            rmax[r] = fmaxf(rmax[r], __shfl_xor(rmax[r], off, 64));
    }
    float rsum[4] = {0.f, 0.f, 0.f, 0.f};
    #pragma unroll
    for (int t = 0; t < 20; ++t) {
        #pragma unroll
        for (int r = 0; r < 4; ++r) {
            float e = __expf(acc[t][r] - rmax[r]);
            acc[t][r] = e;
            rsum[r] += e;
        }
    }
    #pragma unroll
    for (int off = 8; off >= 1; off >>= 1) {
        #pragma unroll
        for (int r = 0; r < 4; ++r)
            rsum[r] += __shfl_xor(rsum[r], off, 64);
    }
    float rinv[4];
    #pragma unroll
    for (int r = 0; r < 4; ++r) rinv[r] = 1.0f / rsum[r];

    __syncthreads();   // all waves done reading Ksh before P/VT overwrite it

    // ---- P @ V in two 160-key chunks (P + VT chunk alias dead K region) ----
    floatx4 oacc[4] = {};
    for (int cch = 0; cch < 2; ++cch) {
        // write P chunk (C-layout -> row-major f16 in LDS)
        #pragma unroll
        for (int t = 0; t < 10; ++t) {
            int tt = cch * 10 + t;
            #pragma unroll
            for (int r = 0; r < 4; ++r)
                Psh[(wv * 16 + quad * 4 + r) * PSTR2 + t * 16 + m] =
                    (_Float16)(acc[tt][r] * rinv[r]);
        }
        // stage V^T chunk: keys [cch*160, cch*160+160)
        for (int i = tid; i < 160 * 16; i += 256) {
            int key = (i >> 4) + cch * 160;   // gathered key index 0..319
            int c4  = (i & 15) << 2;
            int srow = (key < BLK) ? (nblk * BLK + key) : gather_row(key - BLK);
            const float4 f = *(const float4*)(Vh + (size_t)srow * DH + c4);
            int kl = key - cch * 160;
            VTc[(c4 + 0) * PSTR2 + kl] = (_Float16)f.x;
            VTc[(c4 + 1) * PSTR2 + kl] = (_Float16)f.y;
            VTc[(c4 + 2) * PSTR2 + kl] = (_Float16)f.z;
            VTc[(c4 + 3) * PSTR2 + kl] = (_Float16)f.w;
        }
        __syncthreads();
        // MFMA: 5 k-steps of 32 keys; A = P (own wave's rows), B = VT chunk
        #pragma unroll
        for (int kc = 0; kc < 5; ++kc) {
            f16x8 pf = *(const f16x8*)(&Psh[(wv * 16 + m) * PSTR2 + kc * 32 + quad * 8]);
            #pragma unroll
            for (int t = 0; t < 4; ++t) {
                f16x8 vf = *(const f16x8*)(&VTc[(t * 16 + m) * PSTR2 + kc * 32 + quad * 8]);
                oacc[t] = __builtin_amdgcn_mfma_f32_16x16x32_f16(pf, vf, oacc[t], 0, 0, 0);
            }
        }
        __syncthreads();
    }

    // ---- store O (fp32): lane writes rows quad*4+r, cols t*16+m ----
    #pragma unroll
    for (int t = 0; t < 4; ++t) {
        #pragma unroll
        for (int r = 0; r < 4; ++r)
            Oh[(size_t)(nblk * BLK + wv * 16 + quad * 4 + r) * DH + t * 16 + m] = oacc[t][r];
    }
}

extern "C" void kernel_launch(void* const* d_in, const int* in_sizes, int n_in,
                              void* d_out, int out_size, void* d_ws, size_t ws_size,
                              hipStream_t stream) {
    const float* q    = (const float*)d_in[0];
    const float* k    = (const float*)d_in[1];
    const float* v    = (const float*)d_in[2];
    const float* mask = (const float*)d_in[3];
    float* out = (float*)d_out;
    (void)in_sizes; (void)n_in; (void)out_size; (void)d_ws; (void)ws_size;
    sparse_attn_kernel<<<BSZ * NH * NB, 256, 0, stream>>>(q, k, v, mask, out);
}